// Round 15
// baseline (192.537 us; speedup 1.0000x reference)
//
#include <hip/hip_runtime.h>
#include <stdint.h>

// Problem dims (fixed)
#define LL   1024
#define BB   8
#define EE   512
#define HH   8
#define HDD  64
#define NEXP 8
#define TT   8192   // L*B tokens

typedef unsigned short u16t;
typedef __bf16 bf16x8 __attribute__((ext_vector_type(8)));
typedef u16t   u16x8  __attribute__((ext_vector_type(8)));
typedef u16t   u16x4  __attribute__((ext_vector_type(4)));
typedef float  f32x4  __attribute__((ext_vector_type(4)));

#define LAM 0.18033688011112042f   // log2(e)/8 : folded into Q projection

__device__ __forceinline__ u16t f2bf(float f) {
  union { float f; unsigned int u; } a; a.f = f;
  unsigned int r = a.u + 0x7fffu + ((a.u >> 16) & 1u);
  return (u16t)(r >> 16);
}
__device__ __forceinline__ float bf2f(u16t s) {
  union { unsigned int u; float f; } a; a.u = ((unsigned int)s) << 16; return a.f;
}

__device__ __forceinline__ f32x4 mfma16(bf16x8 a, bf16x8 b, f32x4 c) {
  return __builtin_amdgcn_mfma_f32_16x16x32_bf16(a, b, c, 0, 0, 0);
}

#define GLDS16(gp, lp) \
  __builtin_amdgcn_global_load_lds( \
      (const __attribute__((address_space(1))) unsigned int*)(const void*)(gp), \
      (__attribute__((address_space(3))) unsigned int*)(void*)(lp), 16, 0, 0)

// ---------------- all f32->bf16 converts + wq/wk/wv transpose in ONE dispatch ----------------
__global__ __launch_bounds__(256) void cvt_all(
    const float* __restrict__ x, const float* __restrict__ in_w,
    const float* __restrict__ out_w, const float* __restrict__ shw,
    const float* __restrict__ expw,
    const float* __restrict__ wq, const float* __restrict__ wk,
    const float* __restrict__ wv,
    u16t* __restrict__ xb, u16t* __restrict__ inwb, u16t* __restrict__ outwb,
    u16t* __restrict__ shwb, u16t* __restrict__ expwb, u16t* __restrict__ w3t) {
  __shared__ float tile[64][65];
  const int bid = blockIdx.x;
  if (bid >= 7424) {
    const int i = bid - 7424;           // 0..191
    const int z = i >> 6, rem = i & 63;
    const int by = rem >> 3, bx = rem & 7;
    const float* src = z == 0 ? wq : z == 1 ? wk : wv;
    u16t* dst = w3t + (size_t)z * 262144;
    const int r = threadIdx.x >> 4;
    const int c = (threadIdx.x & 15) * 4;
    const int r0 = by * 64, c0 = bx * 64;
#pragma unroll
    for (int k = 0; k < 4; k++) {
      float4 v = *(const float4*)&src[(size_t)(r0 + r + k * 16) * 512 + c0 + c];
      tile[r + k * 16][c] = v.x; tile[r + k * 16][c + 1] = v.y;
      tile[r + k * 16][c + 2] = v.z; tile[r + k * 16][c + 3] = v.w;
    }
    __syncthreads();
#pragma unroll
    for (int k = 0; k < 4; k++) {
      const int orow = c0 + r + k * 16;
      u16x4 o = { f2bf(tile[c][r + k * 16]), f2bf(tile[c + 1][r + k * 16]),
                  f2bf(tile[c + 2][r + k * 16]), f2bf(tile[c + 3][r + k * 16]) };
      *(u16x4*)&dst[(size_t)orow * 512 + r0 + c] = o;
    }
    return;
  }
  const float* s; u16t* d; int i;
  if (bid < 4096)      { s = x;     d = xb;    i = bid; }
  else if (bid < 4864) { s = in_w;  d = inwb;  i = bid - 4096; }
  else if (bid < 5120) { s = out_w; d = outwb; i = bid - 4864; }
  else if (bid < 5376) { s = shw;   d = shwb;  i = bid - 5120; }
  else                 { s = expw;  d = expwb; i = bid - 5376; }
  const int idx = (i * 256 + threadIdx.x) * 4;
  float4 v = *(const float4*)&s[idx];
  u16x4 o = { f2bf(v.x), f2bf(v.y), f2bf(v.z), f2bf(v.w) };
  *(u16x4*)&d[idx] = o;
}

// ---------------- composed-weight GEMM (64x64 tiles); z==0 (Q) scaled by LAM ----------------
__global__ __launch_bounds__(256) void compose_k(const u16t* __restrict__ Aall,
                                                 const u16t* __restrict__ Wall,
                                                 u16t* __restrict__ Call) {
  const u16t* A = Aall + (size_t)blockIdx.z * 262144;
  const u16t* W = Wall + (size_t)blockIdx.z * 262144;
  u16t* C = Call + (size_t)blockIdx.z * 262144;
  const float scale = blockIdx.z == 0 ? LAM : 1.0f;
  __shared__ alignas(16) u16t As[64 * 32];
  __shared__ alignas(16) u16t Ws[64 * 32];
  const int tid = threadIdx.x;
  const int lane = tid & 63, wave = tid >> 6;
  const int r15 = lane & 15, rhi = lane >> 4;
  const int wr = wave >> 1, wc = wave & 1;
  const int m0 = blockIdx.x * 64, n0 = blockIdx.y * 64;
  const int arow = tid >> 2, acol = (tid & 3) * 8;
  const f32x4 fz = {0.f, 0.f, 0.f, 0.f};
  f32x4 acc[2][2] = {{fz, fz}, {fz, fz}};
  const u16t* Ap = A + (size_t)(m0 + arow) * 512 + acol;
  const u16t* Wp = W + (size_t)(n0 + arow) * 512 + acol;
  u16t* As0 = &As[tid * 8];
  u16t* Ws0 = &Ws[tid * 8];
  for (int kt = 0; kt < 512; kt += 32) {
    __syncthreads();
    GLDS16(Ap + kt, As0);
    GLDS16(Wp + kt, Ws0);
    asm volatile("s_waitcnt vmcnt(0)" ::: "memory");
    __syncthreads();
    bf16x8 af[2], bfv[2];
#pragma unroll
    for (int mi = 0; mi < 2; mi++)
      af[mi] = *(const bf16x8*)&As[(wr * 32 + mi * 16 + r15) * 32 + rhi * 8];
#pragma unroll
    for (int ni = 0; ni < 2; ni++)
      bfv[ni] = *(const bf16x8*)&Ws[(wc * 32 + ni * 16 + r15) * 32 + rhi * 8];
#pragma unroll
    for (int mi = 0; mi < 2; mi++)
#pragma unroll
      for (int ni = 0; ni < 2; ni++)
        acc[mi][ni] = mfma16(af[mi], bfv[ni], acc[mi][ni]);
  }
#pragma unroll
  for (int mi = 0; mi < 2; mi++)
#pragma unroll
    for (int ni = 0; ni < 2; ni++) {
      const int col = n0 + wc * 32 + ni * 16 + r15;
#pragma unroll
      for (int r = 0; r < 4; r++) {
        const int row = m0 + wr * 32 + mi * 16 + rhi * 4 + r;
        C[(size_t)row * 512 + col] = f2bf(acc[mi][ni][r] * scale);
      }
    }
}

// ---------------- composed bias (seg 0 scaled by LAM) ----------------
__global__ __launch_bounds__(256) void bias_mv(const float* __restrict__ in_w,
                                               const float* __restrict__ in_b,
                                               const float* __restrict__ b0,
                                               const float* __restrict__ b1,
                                               const float* __restrict__ b2v,
                                               float* __restrict__ out) {
  const int bi = blockIdx.x;                 // 24 blocks
  const int seg = bi >> 3, m0 = (bi & 7) * 64;
  const float* bvec = seg == 0 ? b0 : seg == 1 ? b1 : b2v;
  const int m = m0 + (threadIdx.x >> 2), q = threadIdx.x & 3;
  const float* row = in_w + (size_t)(seg * 512 + m) * 512 + q * 128;
  const float* bv = bvec + q * 128;
  float s = 0.f;
  for (int j = 0; j < 128; j++) s += row[j] * bv[j];
  s += __shfl_xor(s, 1); s += __shfl_xor(s, 2);
  if (q == 0) {
    float r2 = s + in_b[seg * 512 + m];
    out[seg * 512 + m] = seg == 0 ? r2 * LAM : r2;
  }
}

// ---------------- 128x128-tile GEMM, double-buffered LDS + counted vmcnt ----------------
template<int ACT, int OUTBF>
__global__ __launch_bounds__(256) void gemm_bt(
    const u16t* __restrict__ A, int lda,
    const u16t* __restrict__ W,
    const float* __restrict__ bias,
    void* __restrict__ Cp, int ldc, int K)
{
  __shared__ alignas(16) u16t As[2 * 128 * 32];
  __shared__ alignas(16) u16t Ws[2 * 128 * 32];
  const int tid  = threadIdx.x;
  const int lane = tid & 63, wave = tid >> 6;
  const int r15  = lane & 15, rhi = lane >> 4;
  const int wr   = wave >> 1, wc  = wave & 1;
  const int m0 = blockIdx.x * 128, n0 = blockIdx.y * 128;
  const int arow = tid >> 2, acol = (tid & 3) * 8;

  const f32x4 fz = {0.f, 0.f, 0.f, 0.f};
  f32x4 acc[4][4];
#pragma unroll
  for (int i = 0; i < 4; i++)
#pragma unroll
    for (int j = 0; j < 4; j++) acc[i][j] = fz;

  const u16t* Ap0 = A + (size_t)(m0 + arow) * lda + acol;
  const u16t* Ap1 = A + (size_t)(m0 + arow + 64) * lda + acol;
  const u16t* Wp0 = W + (size_t)(n0 + arow) * K + acol;
  const u16t* Wp1 = W + (size_t)(n0 + arow + 64) * K + acol;

  GLDS16(Ap0, &As[tid * 8]);
  GLDS16(Ap1, &As[(tid + 256) * 8]);
  GLDS16(Wp0, &Ws[tid * 8]);
  GLDS16(Wp1, &Ws[(tid + 256) * 8]);

  int cur = 0;
  for (int kt = 0; kt < K; kt += 32) {
    const int nxt = cur ^ 1;
    if (kt) __syncthreads();
    if (kt + 32 < K) {
      const int no = nxt * 4096;
      GLDS16(Ap0 + kt + 32, &As[no + tid * 8]);
      GLDS16(Ap1 + kt + 32, &As[no + (tid + 256) * 8]);
      GLDS16(Wp0 + kt + 32, &Ws[no + tid * 8]);
      GLDS16(Wp1 + kt + 32, &Ws[no + (tid + 256) * 8]);
      asm volatile("s_waitcnt vmcnt(4)" ::: "memory");
    } else {
      asm volatile("s_waitcnt vmcnt(0)" ::: "memory");
    }
    __syncthreads();
    const int cb = cur * 4096;
    bf16x8 af[4], bfv[4];
#pragma unroll
    for (int mi = 0; mi < 4; mi++)
      af[mi] = *(const bf16x8*)&As[cb + (wr * 64 + mi * 16 + r15) * 32 + rhi * 8];
#pragma unroll
    for (int ni = 0; ni < 4; ni++)
      bfv[ni] = *(const bf16x8*)&Ws[cb + (wc * 64 + ni * 16 + r15) * 32 + rhi * 8];
#pragma unroll
    for (int mi = 0; mi < 4; mi++)
#pragma unroll
      for (int ni = 0; ni < 4; ni++)
        acc[mi][ni] = mfma16(af[mi], bfv[ni], acc[mi][ni]);
    cur = nxt;
  }

#pragma unroll
  for (int mi = 0; mi < 4; mi++) {
#pragma unroll
    for (int ni = 0; ni < 4; ni++) {
      const int col = n0 + wc * 64 + ni * 16 + r15;
      const float bv = bias[col];
#pragma unroll
      for (int r = 0; r < 4; r++) {
        const int row = m0 + wr * 64 + mi * 16 + rhi * 4 + r;
        float v = acc[mi][ni][r] + bv;
        if (ACT == 1) v = v >= 0.f ? v : 0.01f * v;
        if (OUTBF) ((u16t*)Cp)[(size_t)row * ldc + col] = f2bf(v);
        else       ((float*)Cp)[(size_t)row * ldc + col] = v;
      }
    }
  }
}

// ---------------- 64x64-tile GEMM (out-proj), double-buffered ----------------
template<int ACT>
__global__ __launch_bounds__(256) void gemm64(
    const u16t* __restrict__ A, int lda,
    const u16t* __restrict__ W,
    const float* __restrict__ bias,
    u16t* __restrict__ Cp, int ldc, int K)
{
  __shared__ alignas(16) u16t As[2 * 64 * 32];
  __shared__ alignas(16) u16t Ws[2 * 64 * 32];
  const int tid  = threadIdx.x;
  const int lane = tid & 63, wave = tid >> 6;
  const int r15  = lane & 15, rhi = lane >> 4;
  const int wr   = wave >> 1, wc  = wave & 1;
  const int m0 = blockIdx.x * 64, n0 = blockIdx.y * 64;
  const int arow = tid >> 2, acol = (tid & 3) * 8;

  const f32x4 fz = {0.f, 0.f, 0.f, 0.f};
  f32x4 acc[2][2] = {{fz, fz}, {fz, fz}};

  const u16t* Ap = A + (size_t)(m0 + arow) * lda + acol;
  const u16t* Wp = W + (size_t)(n0 + arow) * K + acol;

  GLDS16(Ap, &As[tid * 8]);
  GLDS16(Wp, &Ws[tid * 8]);

  int cur = 0;
  for (int kt = 0; kt < K; kt += 32) {
    const int nxt = cur ^ 1;
    if (kt) __syncthreads();
    if (kt + 32 < K) {
      const int no = nxt * 2048;
      GLDS16(Ap + kt + 32, &As[no + tid * 8]);
      GLDS16(Wp + kt + 32, &Ws[no + tid * 8]);
      asm volatile("s_waitcnt vmcnt(2)" ::: "memory");
    } else {
      asm volatile("s_waitcnt vmcnt(0)" ::: "memory");
    }
    __syncthreads();
    const int cb = cur * 2048;
    bf16x8 af[2], bfv[2];
#pragma unroll
    for (int mi = 0; mi < 2; mi++)
      af[mi] = *(const bf16x8*)&As[cb + (wr * 32 + mi * 16 + r15) * 32 + rhi * 8];
#pragma unroll
    for (int ni = 0; ni < 2; ni++)
      bfv[ni] = *(const bf16x8*)&Ws[cb + (wc * 32 + ni * 16 + r15) * 32 + rhi * 8];
#pragma unroll
    for (int mi = 0; mi < 2; mi++)
#pragma unroll
      for (int ni = 0; ni < 2; ni++)
        acc[mi][ni] = mfma16(af[mi], bfv[ni], acc[mi][ni]);
    cur = nxt;
  }

#pragma unroll
  for (int mi = 0; mi < 2; mi++)
#pragma unroll
    for (int ni = 0; ni < 2; ni++) {
      const int col = n0 + wc * 32 + ni * 16 + r15;
      const float bv = bias[col];
#pragma unroll
      for (int r = 0; r < 4; r++) {
        const int row = m0 + wr * 32 + mi * 16 + rhi * 4 + r;
        float v = acc[mi][ni][r] + bv;
        if (ACT == 1) v = v >= 0.f ? v : 0.01f * v;
        Cp[(size_t)row * ldc + col] = f2bf(v);
      }
    }
}

// ---------------- gather x1b rows into expert-sorted xg (COMPACT rows = prefix+pos) ----------------
__global__ __launch_bounds__(256) void gather_x(
    const u16t* __restrict__ x1b, const int* __restrict__ list,
    const int* __restrict__ counts, u16t* __restrict__ xg)
{
  const int e = blockIdx.x, c = blockIdx.y;
  const int cnt = counts[e];
  const int pos0 = c * 128;
  if (pos0 >= cnt) return;
  int rowbase = 0;
  for (int j = 0; j < e; j++) rowbase += counts[j];
  const int chunk = threadIdx.x & 63;          // 64 chunks of 8 u16 per row
  const int rsub = threadIdx.x >> 6;           // 4 rows per pass
  for (int p = 0; p < 32; p++) {
    const int pos = pos0 + p * 4 + rsub;
    if (pos < cnt) {
      const int tok = list[e * 8192 + pos] >> 1;
      *(u16x8*)&xg[(size_t)(rowbase + pos) * 512 + chunk * 8] =
          *(const u16x8*)&x1b[(size_t)tok * 512 + chunk * 8];
    }
  }
}

// ---------------- MoE (expert-sorted compact, fully streaming) + shared expert ----------------
#define MOE_MAX_TILES 200   // worst case: sum ceil(cnt_e/128) <= 136, + 64 shared; 200 = 8*25
__global__ __launch_bounds__(256) void moe_shared(
    const u16t* __restrict__ xg, const u16t* __restrict__ expwb,
    const float* __restrict__ expb,
    const u16t* __restrict__ x1b,
    const u16t* __restrict__ shwb, const float* __restrict__ shb,
    const int* __restrict__ counts, const float* __restrict__ wlist,
    u16t* __restrict__ yg, u16t* __restrict__ shrd)
{
  // XCD-chunked swizzle keeps an expert's m-tiles on one XCD (W L2 reuse)
  const int raw = blockIdx.x;
  const int idx = (raw & 7) * 25 + (raw >> 3);
  int e = 0, base = 0, cnt = 0, rowbase = 0;
  for (; e < 8; e++) {
    cnt = counts[e];
    const int nt = (cnt + 127) >> 7;
    if (idx < base + nt) break;
    base += nt;
    rowbase += cnt;
  }
  const bool sh = (e == 8);
  if (sh) {
    cnt = TT;
    if (idx - base >= 64) return;
  }
  const int m0 = (idx - base) * 128;
  if (m0 >= cnt) return;

  const int n0 = blockIdx.y * 128;
  __shared__ alignas(16) u16t As[2 * 128 * 32];
  __shared__ alignas(16) u16t Ws[2 * 128 * 32];
  __shared__ float wws[128];
  const int tid  = threadIdx.x;
  const int lane = tid & 63, wave = tid >> 6;
  const int r15  = lane & 15, rhi = lane >> 4;
  const int wr   = wave >> 1, wc  = wave & 1;
  const int arow = tid >> 2, acol = (tid & 3) * 8;

  if (tid < 128) {
    if (sh) wws[tid] = 1.f;
    else {
      int i2 = m0 + tid; if (i2 >= cnt) i2 = cnt - 1;
      wws[tid] = wlist[e * 8192 + i2];
    }
  }
  __syncthreads();

  const f32x4 fz = {0.f, 0.f, 0.f, 0.f};
  f32x4 acc[4][4];
#pragma unroll
  for (int i = 0; i < 4; i++)
#pragma unroll
    for (int j = 0; j < 4; j++) acc[i][j] = fz;

  // contiguous A rows (tail rows clamped to stay in the 16384-row buffer)
  const u16t *Ap0, *Ap1;
  if (sh) {
    Ap0 = x1b + (size_t)(m0 + arow) * 512 + acol;
    Ap1 = Ap0 + (size_t)64 * 512;
  } else {
    int rA = rowbase + m0 + arow;      if (rA > 16383) rA = 16383;
    int rB = rowbase + m0 + arow + 64; if (rB > 16383) rB = 16383;
    Ap0 = xg + (size_t)rA * 512 + acol;
    Ap1 = xg + (size_t)rB * 512 + acol;
  }
  const u16t* W  = (sh ? shwb : expwb + (size_t)e * 262144);
  const float* bias = sh ? shb : expb + e * 512;
  const u16t* Wp0 = W + (size_t)(n0 + arow) * 512 + acol;
  const u16t* Wp1 = Wp0 + (size_t)64 * 512;

  GLDS16(Ap0, &As[tid * 8]);
  GLDS16(Ap1, &As[(tid + 256) * 8]);
  GLDS16(Wp0, &Ws[tid * 8]);
  GLDS16(Wp1, &Ws[(tid + 256) * 8]);

  int cur = 0;
  for (int kt = 0; kt < 512; kt += 32) {
    const int nxt = cur ^ 1;
    if (kt) __syncthreads();
    if (kt + 32 < 512) {
      const int no = nxt * 4096;
      GLDS16(Ap0 + kt + 32, &As[no + tid * 8]);
      GLDS16(Ap1 + kt + 32, &As[no + (tid + 256) * 8]);
      GLDS16(Wp0 + kt + 32, &Ws[no + tid * 8]);
      GLDS16(Wp1 + kt + 32, &Ws[no + (tid + 256) * 8]);
      asm volatile("s_waitcnt vmcnt(4)" ::: "memory");
    } else {
      asm volatile("s_waitcnt vmcnt(0)" ::: "memory");
    }
    __syncthreads();
    const int cb = cur * 4096;
    bf16x8 af[4], bfv[4];
#pragma unroll
    for (int mi = 0; mi < 4; mi++)
      af[mi] = *(const bf16x8*)&As[cb + (wr * 64 + mi * 16 + r15) * 32 + rhi * 8];
#pragma unroll
    for (int ni = 0; ni < 4; ni++)
      bfv[ni] = *(const bf16x8*)&Ws[cb + (wc * 64 + ni * 16 + r15) * 32 + rhi * 8];
#pragma unroll
    for (int mi = 0; mi < 4; mi++)
#pragma unroll
      for (int ni = 0; ni < 4; ni++)
        acc[mi][ni] = mfma16(af[mi], bfv[ni], acc[mi][ni]);
    cur = nxt;
  }

  // contiguous output rows
  u16t* Obase = sh ? (shrd + (size_t)m0 * 512)
                   : (yg + (size_t)(rowbase + m0) * 512);
#pragma unroll
  for (int mi = 0; mi < 4; mi++)
#pragma unroll
    for (int ni = 0; ni < 4; ni++) {
      const int col = n0 + wc * 64 + ni * 16 + r15;
      const float bv = bias[col];
#pragma unroll
      for (int r = 0; r < 4; r++) {
        const int rl = wr * 64 + mi * 16 + rhi * 4 + r;
        if (m0 + rl < cnt) {
          float z = acc[mi][ni][r] + bv;
          z = z >= 0.f ? z : 0.01f * z;
          Obase[(size_t)rl * 512 + col] = f2bf(wws[rl] * z);
        }
      }
    }
}

// ---------------- flash attention v3: 8 waves / 128 q-rows per block ----------------
__global__ __launch_bounds__(512) void attn_kernel(
    const u16t* __restrict__ qkv, u16t* __restrict__ ao)
{
  const int bh = blockIdx.x;
  const int b = bh >> 3, h = bh & 7;
  const int qg = blockIdx.y;
  const int tid  = threadIdx.x;
  const int lane = tid & 63, wave = tid >> 6;
  const int r15  = lane & 15, rhi = lane >> 4;

  __shared__ alignas(16) u16t Ks[128 * 72];
  __shared__ alignas(16) u16t Vt[64 * 136];

  const int qrow = qg * 128 + (wave >> 2) * 64 + (wave & 3) * 16 + r15;
  const size_t qoff = ((size_t)qrow * BB + b) * 1536 + h * HDD;
  const bf16x8 qf0 = *(const bf16x8*)&qkv[qoff + rhi * 8];
  const bf16x8 qf1 = *(const bf16x8*)&qkv[qoff + 32 + rhi * 8];

  const f32x4 fz = {0.f, 0.f, 0.f, 0.f};
  f32x4 oa[4] = {fz, fz, fz, fz};
  float psum = 0.f;

  const int krow = tid >> 2, kchunk = (tid & 3) * 16;
  const int vd0 = (wave & 3) * 16 + (lane >> 5) * 8;
  const int vkv = (wave >> 2) * 64 + (lane & 31) * 2;

  u16x8 kA0, kA1, vA0, vA1;
  {
    const size_t kb = ((size_t)krow * BB + b) * 1536 + h * HDD + 512 + kchunk;
    kA0 = *(const u16x8*)&qkv[kb];
    kA1 = *(const u16x8*)&qkv[kb + 8];
    const size_t v0 = ((size_t)vkv * BB + b) * 1536 + h * HDD + 1024 + vd0;
    vA0 = *(const u16x8*)&qkv[v0];
    vA1 = *(const u16x8*)&qkv[v0 + (size_t)BB * 1536];
  }

  for (int t = 0; t < 8; t++) {
    __syncthreads();
    {
      u16t* kd = &Ks[krow * 72 + kchunk];
      *(u16x8*)&kd[0] = kA0;
      *(u16x8*)&kd[8] = kA1;
    }
#pragma unroll
    for (int j = 0; j < 8; j++) {
      unsigned int w = (unsigned int)vA0[j] | ((unsigned int)vA1[j] << 16);
      *(unsigned int*)&Vt[(vd0 + j) * 136 + vkv] = w;
    }
    if (t < 7) {
      const int kv0n = (t + 1) * 128;
      const size_t kb = ((size_t)(kv0n + krow) * BB + b) * 1536 + h * HDD + 512 + kchunk;
      kA0 = *(const u16x8*)&qkv[kb];
      kA1 = *(const u16x8*)&qkv[kb + 8];
      const size_t v0 = ((size_t)(kv0n + vkv) * BB + b) * 1536 + h * HDD + 1024 + vd0;
      vA0 = *(const u16x8*)&qkv[v0];
      vA1 = *(const u16x8*)&qkv[v0 + (size_t)BB * 1536];
    }
    __syncthreads();

    f32x4 s[8];
    __builtin_amdgcn_s_setprio(1);
#pragma unroll
    for (int nt = 0; nt < 8; nt++) {
      const u16t* kr = &Ks[(nt * 16 + r15) * 72];
      bf16x8 k0 = *(const bf16x8*)&kr[rhi * 8];
      bf16x8 k1 = *(const bf16x8*)&kr[32 + rhi * 8];
      f32x4 acc = fz;
      acc = mfma16(k0, qf0, acc);
      acc = mfma16(k1, qf1, acc);
      s[nt] = acc;
    }
    __builtin_amdgcn_s_setprio(0);

    unsigned int P2[8][2];
#pragma unroll
    for (int nt = 0; nt < 8; nt++) {
#pragma unroll
      for (int r = 0; r < 4; r++) {
        s[nt][r] = exp2f(s[nt][r]);
        psum += s[nt][r];
      }
      asm("v_cvt_pk_bf16_f32 %0, %1, %2" : "=v"(P2[nt][0]) : "v"(s[nt][0]), "v"(s[nt][1]));
      asm("v_cvt_pk_bf16_f32 %0, %1, %2" : "=v"(P2[nt][1]) : "v"(s[nt][2]), "v"(s[nt][3]));
    }

    __builtin_amdgcn_s_setprio(1);
#pragma unroll
    for (int c = 0; c < 4; c++) {
      union { unsigned int w[4]; bf16x8 v; } pf;
      pf.w[0] = P2[2 * c][0];     pf.w[1] = P2[2 * c][1];
      pf.w[2] = P2[2 * c + 1][0]; pf.w[3] = P2[2 * c + 1][1];
#pragma unroll
      for (int dd = 0; dd < 4; dd++) {
        const u16t* vr = &Vt[(dd * 16 + r15) * 136 + c * 32 + rhi * 4];
        union { u16x4 h[2]; bf16x8 v; } vb;
        vb.h[0] = *(const u16x4*)&vr[0];
        vb.h[1] = *(const u16x4*)&vr[16];
        oa[dd] = mfma16(vb.v, pf.v, oa[dd]);
      }
    }
    __builtin_amdgcn_s_setprio(0);
  }

  float ls = psum;
  ls += __shfl_xor(ls, 16);
  ls += __shfl_xor(ls, 32);
  const float inv = 1.f / ls;
  const size_t obase = ((size_t)qrow * BB + b) * EE + h * HDD;
#pragma unroll
  for (int dd = 0; dd < 4; dd++) {
    u16x4 o = { f2bf(oa[dd][0] * inv), f2bf(oa[dd][1] * inv),
                f2bf(oa[dd][2] * inv), f2bf(oa[dd][3] * inv) };
    *(u16x4*)&ao[obase + dd * 16 + rhi * 4] = o;
  }
}

// ---------------- fused LN1 + gate (wave per token) ----------------
__device__ __forceinline__ float wave_sum(float v) {
#pragma unroll
  for (int off = 1; off < 64; off <<= 1) v += __shfl_xor(v, off);
  return v;
}

__global__ __launch_bounds__(256) void ln1_gate(
    const float* __restrict__ x, const u16t* __restrict__ aopb,
    const float* __restrict__ g, const float* __restrict__ be,
    const float* __restrict__ gw, const float* __restrict__ gb,
    u16t* __restrict__ x1b,
    int* __restrict__ tok_pack, float2* __restrict__ tok_w,
    float* __restrict__ partials)
{
  const int wave = threadIdx.x >> 6, lane = threadIdx.x & 63;
  const int t = blockIdx.x * 4 + wave;
  const size_t base = (size_t)t * EE + lane * 8;
  float4 a0 = *(const float4*)&x[base], a1 = *(const float4*)&x[base + 4];
  u16x8 ap = *(const u16x8*)&aopb[base];
  float v[8] = { a0.x + bf2f(ap[0]), a0.y + bf2f(ap[1]), a0.z + bf2f(ap[2]), a0.w + bf2f(ap[3]),
                 a1.x + bf2f(ap[4]), a1.y + bf2f(ap[5]), a1.z + bf2f(ap[6]), a1.w + bf2f(ap[7]) };
  float s = 0.f;
#pragma unroll
  for (int i = 0; i < 8; i++) s += v[i];
  const float mean = wave_sum(s) * (1.f / EE);
  float vs = 0.f;
#pragma unroll
  for (int i = 0; i < 8; i++) { v[i] -= mean; vs += v[i] * v[i]; }
  const float inv = rsqrtf(wave_sum(vs) * (1.f / EE) + 1e-5f);
  float4 g0 = *(const float4*)&g[lane * 8],  g1 = *(const float4*)&g[lane * 8 + 4];
  float4 b0 = *(const float4*)&be[lane * 8], b1 = *(const float4*)&be[lane * 8 + 4];
  float o[8] = { v[0]*inv*g0.x + b0.x, v[1]*inv*g0.y + b0.y, v[2]*inv*g0.z + b0.z, v[3]*inv*g0.w + b0.w,
                 v[4]*inv*g1.x + b1.x, v[5]*inv*g1.y + b1.y, v[6]*inv*g1.z + b1.z, v[7]*inv*g1.w + b1.w };
  u16x8 ob = { f2bf(o[0]), f2bf(o[1]), f2bf(o[2]), f2bf(o[3]),
               f2bf(o[4]), f2bf(o[5]), f2bf(o[6]), f2bf(o[7]) };
  *(u16x8*)&x1b[base] = ob;

  float pe[8];
  float mx = -1e30f;
#pragma unroll
  for (int e = 0; e < 8; e++) {
    float4 ga = *(const float4*)&gw[e * EE + lane * 8];
    float4 gB = *(const float4*)&gw[e * EE + lane * 8 + 4];
    float d = o[0]*ga.x + o[1]*ga.y + o[2]*ga.z + o[3]*ga.w
            + o[4]*gB.x + o[5]*gB.y + o[6]*gB.z + o[7]*gB.w;
#pragma unroll
    for (int off = 1; off < 64; off <<= 1) d += __shfl_xor(d, off);
    pe[e] = d + gb[e];
    mx = fmaxf(mx, pe[e]);
  }
  float se = 0.f;
#pragma unroll
  for (int e = 0; e < 8; e++) { pe[e] = __expf(pe[e] - mx); se += pe[e]; }
  const float invs = 1.f / se;
#pragma unroll
  for (int e = 0; e < 8; e++) pe[e] *= invs;
  float v1 = -1.f; int i1 = 0;
#pragma unroll
  for (int e = 0; e < 8; e++) if (pe[e] > v1) { v1 = pe[e]; i1 = e; }
  float v2 = -1.f; int i2 = -1;
#pragma unroll
  for (int e = 0; e < 8; e++) if (e != i1 && pe[e] > v2) { v2 = pe[e]; i2 = e; }
  const float denom = 1.f / (v1 + v2);
  if (lane == 0) {
    tok_pack[t] = i1 | (i2 << 8);
    float2 w; w.x = v1 * denom; w.y = v2 * denom;
    tok_w[t] = w;
  }
  __shared__ float fb[4][8], pb[4][8];
  if (lane < 8) {
    fb[wave][lane] = (lane == i1 || lane == i2) ? 1.f : 0.f;
    pb[wave][lane] = pe[lane];
  }
  __syncthreads();
  if (threadIdx.x < 8) {
    const int e = threadIdx.x;
    partials[(size_t)blockIdx.x * 16 + e]     = fb[0][e] + fb[1][e] + fb[2][e] + fb[3][e];
    partials[(size_t)blockIdx.x * 16 + 8 + e] = pb[0][e] + pb[1][e] + pb[2][e] + pb[3][e];
  }
}

// ---------------- LN2 (bf16 inputs; expert rows via prefix(counts)+pos) ----------------
__global__ __launch_bounds__(256) void ln2_kernel(
    const u16t* __restrict__ x1b, const u16t* __restrict__ yg,
    const int* __restrict__ slotpos, const int* __restrict__ counts,
    const u16t* __restrict__ sh,
    const float* __restrict__ g, const float* __restrict__ be,
    float* __restrict__ out)
{
  __shared__ int pf[8];
  if (threadIdx.x < 8) {
    int s2 = 0;
    for (int j = 0; j < (int)threadIdx.x; j++) s2 += counts[j];
    pf[threadIdx.x] = s2;
  }
  __syncthreads();
  const int wave = threadIdx.x >> 6, lane = threadIdx.x & 63;
  const int t = blockIdx.x * 4 + wave;
  const size_t base = (size_t)t * EE + lane * 8;
  const int v0p = slotpos[2 * t], v1p = slotpos[2 * t + 1];
  const int row0 = pf[v0p >> 13] + (v0p & 8191);
  const int row1 = pf[v1p >> 13] + (v1p & 8191);
  u16x8 xv = *(const u16x8*)&x1b[base];
  u16x8 m0 = *(const u16x8*)&yg[(size_t)row0 * EE + lane * 8];
  u16x8 m1 = *(const u16x8*)&yg[(size_t)row1 * EE + lane * 8];
  u16x8 sv = *(const u16x8*)&sh[base];
  float v[8];
#pragma unroll
  for (int i = 0; i < 8; i++)
    v[i] = bf2f(xv[i]) + bf2f(m0[i]) + bf2f(m1[i]) + bf2f(sv[i]);
  float s = 0.f;
#pragma unroll
  for (int i = 0; i < 8; i++) s += v[i];
  const float mean = wave_sum(s) * (1.f / EE);
  float vs = 0.f;
#pragma unroll
  for (int i = 0; i < 8; i++) { v[i] -= mean; vs += v[i] * v[i]; }
  const float inv = rsqrtf(wave_sum(vs) * (1.f / EE) + 1e-5f);
  float4 g0 = *(const float4*)&g[lane * 8],  g1 = *(const float4*)&g[lane * 8 + 4];
  float4 b0 = *(const float4*)&be[lane * 8], b1 = *(const float4*)&be[lane * 8 + 4];
  *(float4*)&out[base] = make_float4(v[0]*inv*g0.x + b0.x, v[1]*inv*g0.y + b0.y,
                                     v[2]*inv*g0.z + b0.z, v[3]*inv*g0.w + b0.w);
  *(float4*)&out[base + 4] = make_float4(v[4]*inv*g1.x + b1.x, v[5]*inv*g1.y + b1.y,
                                         v[6]*inv*g1.z + b1.z, v[7]*inv*g1.w + b1.w);
}

// ---------------- deterministic list build + slotpos + loss reduce (grid 9, block 512) ----------------
__global__ __launch_bounds__(512) void build_lists(
    const int* __restrict__ tok_pack, const float2* __restrict__ tok_w,
    int* __restrict__ counts, int* __restrict__ list, float* __restrict__ wlist,
    int* __restrict__ slotpos,
    const float* __restrict__ partials, float* __restrict__ loss_out)
{
  if (blockIdx.x == 8) {
    __shared__ float acc2[32][16];
    __shared__ float fin[16];
    const int c = threadIdx.x & 15, grp = threadIdx.x >> 4;   // 0..31
    float s = 0.f;
    for (int i = grp; i < 2048; i += 32) s += partials[(size_t)i * 16 + c];
    acc2[grp][c] = s;
    __syncthreads();
    if (threadIdx.x < 16) {
      float t2 = 0.f;
      for (int g2 = 0; g2 < 32; g2++) t2 += acc2[g2][threadIdx.x];
      fin[threadIdx.x] = t2;
    }
    __syncthreads();
    if (threadIdx.x == 0) {
      float loss = 0.f;
      for (int e = 0; e < 8; e++)
        loss += (fin[e] * (1.f / TT)) * (fin[8 + e] * (1.f / TT));
      loss_out[0] = loss * 8.f;
    }
    return;
  }
  const int e = blockIdx.x;
  const int tid = threadIdx.x;
  const int lane = tid & 63, wave = tid >> 6;   // 8 waves
  __shared__ int wtot[8];
  __shared__ int runb;
  if (tid == 0) runb = 0;
  __syncthreads();
  for (int c = 0; c < 16; c++) {
    const int t = c * 512 + tid;
    const int pk = tok_pack[t];
    const int i1 = pk & 255, i2 = (pk >> 8) & 255;
    const bool s1 = (i1 == e);
    const bool flag = s1 || (i2 == e);
    const unsigned long long mask = __ballot(flag);
    if (lane == 63) wtot[wave] = __popcll(mask);
    __syncthreads();
    int wbase = 0;
#pragma unroll
    for (int w2 = 0; w2 < 8; w2++) if (w2 < wave) wbase += wtot[w2];
    int btot = 0;
#pragma unroll
    for (int w2 = 0; w2 < 8; w2++) btot += wtot[w2];
    if (flag) {
      const int pre = __popcll(mask & ((1ull << lane) - 1ull));
      const int pos = runb + wbase + pre;
      const int slot = 2 * t + (s1 ? 0 : 1);
      list[e * 8192 + pos] = slot;
      slotpos[slot] = e * 8192 + pos;    // packed (e,pos); row = prefix[e]+pos
      float2 w = tok_w[t];
      wlist[e * 8192 + pos] = s1 ? w.x : w.y;
    }
    __syncthreads();
    if (tid == 0) runb += btot;
    __syncthreads();
  }
  if (tid == 0) counts[e] = runb;
}

// ---------------- host-side launcher ----------------
extern "C" void kernel_launch(void* const* d_in, const int* in_sizes, int n_in,
                              void* d_out, int out_size, void* d_ws, size_t ws_size,
                              hipStream_t stream) {
  const float* x    = (const float*)d_in[0];
  const float* wq   = (const float*)d_in[1];
  const float* bq   = (const float*)d_in[2];
  const float* wk   = (const float*)d_in[3];
  const float* bk   = (const float*)d_in[4];
  const float* wv   = (const float*)d_in[5];
  const float* bv   = (const float*)d_in[6];
  const float* in_w = (const float*)d_in[7];
  const float* in_b = (const float*)d_in[8];
  const float* out_w= (const float*)d_in[9];
  const float* out_b= (const float*)d_in[10];
  const float* ln1g = (const float*)d_in[11];
  const float* ln1b = (const float*)d_in[12];
  const float* ln2g = (const float*)d_in[13];
  const float* ln2b = (const float*)d_in[14];
  const float* shw  = (const float*)d_in[15];
  const float* shb  = (const float*)d_in[16];
  const float* gw   = (const float*)d_in[17];
  const float* gb   = (const float*)d_in[18];
  const float* expw = (const float*)d_in[19];
  const float* expb = (const float*)d_in[20];

  char* ws = (char*)d_ws;
  // --- static region ---
  u16t* xb     = (u16t*)(ws + 0);          // 8 MB
  u16t* inwb   = (u16t*)(ws + 8388608);    // 1.5 MB
  u16t* w3t    = (u16t*)(ws + 9961472);    // 1.5 MB
  u16t* w2big  = (u16t*)(ws + 11534336);   // 1.5 MB
  u16t* outwb  = (u16t*)(ws + 13107200);   // 0.5 MB
  u16t* shwb   = (u16t*)(ws + 13631488);   // 0.5 MB
  u16t* expwb  = (u16t*)(ws + 14155776);   // 4 MB
  float* b2    = (float*)(ws + 18350080);  // 6 KB
  int*  tok_pack = (int*)(ws + 18356224);  // 32 KB
  float2* tok_w  = (float2*)(ws + 18388992); // 64 KB
  int*  counts = (int*)(ws + 18454528);
  int*  list   = (int*)(ws + 18454656);    // 256 KB
  float* wlist = (float*)(ws + 18716800);  // 256 KB
  float* parts = (float*)(ws + 18978944);  // 128 KB
  int* slotpos = (int*)(ws + 19107072);    // 64 KB  (2*TT ints)
  // --- overlay pool ---
  const size_t S = 19173120;
  u16t* qkvb   = (u16t*)(ws + S);                 // 24 MB: stage1 -> attn
  u16t* aopb   = (u16t*)(ws + S);                 // 8 MB: outproj -> ln1 (qkvb dead)
  u16t* x1b    = (u16t*)(ws + S + 16777216);      // 8 MB: ln1 -> gather/moe/ln2
  u16t* yg     = (u16t*)(ws + S);                 // 16 MB: moe out, compact 16384 rows (aopb dead)
  u16t* aob    = (u16t*)(ws + 0);                 // 8 MB: attn -> outproj (xb dead)
  u16t* shrd   = (u16t*)(ws + 0);                 // 8 MB: moe_shared -> ln2 (aob dead)
  u16t* xg     = (u16t*)(ws + S + 25165824);      // 16 MB expert-sorted x, compact 16384 rows
  float* outp  = (float*)d_out;

  dim3 blk(256);
  // all converts + QKV-weight transpose in one dispatch (7424 + 192 blocks)
  cvt_all<<<7616, blk, 0, stream>>>(x, in_w, out_w, shw, expw, wq, wk, wv,
                                    xb, inwb, outwb, shwb, expwb, w3t);
  // weight/bias composition (Q segment pre-scaled by log2e/8)
  compose_k<<<dim3(8, 8, 3), blk, 0, stream>>>(inwb, w3t, w2big);
  bias_mv<<<24, blk, 0, stream>>>(in_w, in_b, bq, bk, bv, b2);
  // fused QKV projection -> q|k|v packed (ldc 1536)
  gemm_bt<0,1><<<dim3(64, 12), blk, 0, stream>>>(xb, EE, w2big, b2, qkvb, 1536, EE);
  // attention (512-thread blocks, 128 q-rows each)
  attn_kernel<<<dim3(64, 8), dim3(512), 0, stream>>>(qkvb, aob);
  // out projection (bf16 out, 64x64 tiles)
  gemm64<0><<<dim3(128, 8), blk, 0, stream>>>(aob, EE, outwb, out_b, aopb, EE, EE);
  // fused LN1 + gate
  ln1_gate<<<2048, blk, 0, stream>>>(x, aopb, ln1g, ln1b, gw, gb, x1b, tok_pack, tok_w, parts);
  // list build + slotpos + loss reduce (grid 9, block 512)
  build_lists<<<9, dim3(512), 0, stream>>>(tok_pack, tok_w, counts, list, wlist,
                                           slotpos, parts, outp + (size_t)TT * EE);
  // gather x1b rows into expert-sorted xg (compact)
  gather_x<<<dim3(8, 64), blk, 0, stream>>>(x1b, list, counts, xg);
  // MoE (fully streaming) + shared expert
  moe_shared<<<dim3(MOE_MAX_TILES, 4), blk, 0, stream>>>(xg, expwb, expb, x1b, shwb, shb,
                                                         counts, wlist, yg, shrd);
  // LN2 -> output (f32), expert rows via prefix(counts)+pos
  ln2_kernel<<<2048, blk, 0, stream>>>(x1b, yg, slotpos, counts, shrd, ln2g, ln2b, outp);
}

// Round 16
// 170.300 us; speedup vs baseline: 1.1306x; 1.1306x over previous
//
#include <hip/hip_runtime.h>
#include <stdint.h>

// Problem dims (fixed)
#define LL   1024
#define BB   8
#define EE   512
#define HH   8
#define HDD  64
#define NEXP 8
#define TT   8192   // L*B tokens

typedef unsigned short u16t;
typedef __bf16 bf16x8 __attribute__((ext_vector_type(8)));
typedef u16t   u16x8  __attribute__((ext_vector_type(8)));
typedef u16t   u16x4  __attribute__((ext_vector_type(4)));
typedef float  f32x4  __attribute__((ext_vector_type(4)));

#define LAM 0.18033688011112042f   // log2(e)/8 : folded into Q projection

__device__ __forceinline__ u16t f2bf(float f) {
  union { float f; unsigned int u; } a; a.f = f;
  unsigned int r = a.u + 0x7fffu + ((a.u >> 16) & 1u);
  return (u16t)(r >> 16);
}
__device__ __forceinline__ float bf2f(u16t s) {
  union { unsigned int u; float f; } a; a.u = ((unsigned int)s) << 16; return a.f;
}

__device__ __forceinline__ f32x4 mfma16(bf16x8 a, bf16x8 b, f32x4 c) {
  return __builtin_amdgcn_mfma_f32_16x16x32_bf16(a, b, c, 0, 0, 0);
}

#define GLDS16(gp, lp) \
  __builtin_amdgcn_global_load_lds( \
      (const __attribute__((address_space(1))) unsigned int*)(const void*)(gp), \
      (__attribute__((address_space(3))) unsigned int*)(void*)(lp), 16, 0, 0)

// ---------------- all f32->bf16 converts + wq/wk/wv transpose in ONE dispatch ----------------
__global__ __launch_bounds__(256) void cvt_all(
    const float* __restrict__ x, const float* __restrict__ in_w,
    const float* __restrict__ out_w, const float* __restrict__ shw,
    const float* __restrict__ expw,
    const float* __restrict__ wq, const float* __restrict__ wk,
    const float* __restrict__ wv,
    u16t* __restrict__ xb, u16t* __restrict__ inwb, u16t* __restrict__ outwb,
    u16t* __restrict__ shwb, u16t* __restrict__ expwb, u16t* __restrict__ w3t) {
  __shared__ float tile[64][65];
  const int bid = blockIdx.x;
  if (bid >= 7424) {
    // transpose-convert: w3t[z][n][j] = bf16(w_z[j][n])
    const int i = bid - 7424;           // 0..191
    const int z = i >> 6, rem = i & 63;
    const int by = rem >> 3, bx = rem & 7;
    const float* src = z == 0 ? wq : z == 1 ? wk : wv;
    u16t* dst = w3t + (size_t)z * 262144;
    const int r = threadIdx.x >> 4;
    const int c = (threadIdx.x & 15) * 4;
    const int r0 = by * 64, c0 = bx * 64;
#pragma unroll
    for (int k = 0; k < 4; k++) {
      float4 v = *(const float4*)&src[(size_t)(r0 + r + k * 16) * 512 + c0 + c];
      tile[r + k * 16][c] = v.x; tile[r + k * 16][c + 1] = v.y;
      tile[r + k * 16][c + 2] = v.z; tile[r + k * 16][c + 3] = v.w;
    }
    __syncthreads();
#pragma unroll
    for (int k = 0; k < 4; k++) {
      const int orow = c0 + r + k * 16;
      u16x4 o = { f2bf(tile[c][r + k * 16]), f2bf(tile[c + 1][r + k * 16]),
                  f2bf(tile[c + 2][r + k * 16]), f2bf(tile[c + 3][r + k * 16]) };
      *(u16x4*)&dst[(size_t)orow * 512 + r0 + c] = o;
    }
    return;
  }
  const float* s; u16t* d; int i;
  if (bid < 4096)      { s = x;     d = xb;    i = bid; }
  else if (bid < 4864) { s = in_w;  d = inwb;  i = bid - 4096; }
  else if (bid < 5120) { s = out_w; d = outwb; i = bid - 4864; }
  else if (bid < 5376) { s = shw;   d = shwb;  i = bid - 5120; }
  else                 { s = expw;  d = expwb; i = bid - 5376; }
  const int idx = (i * 256 + threadIdx.x) * 4;
  float4 v = *(const float4*)&s[idx];
  u16x4 o = { f2bf(v.x), f2bf(v.y), f2bf(v.z), f2bf(v.w) };
  *(u16x4*)&d[idx] = o;
}

// ---------------- composed-weight GEMM (64x64 tiles); z==0 (Q) scaled by LAM ----------------
__global__ __launch_bounds__(256) void compose_k(const u16t* __restrict__ Aall,
                                                 const u16t* __restrict__ Wall,
                                                 u16t* __restrict__ Call) {
  const u16t* A = Aall + (size_t)blockIdx.z * 262144;
  const u16t* W = Wall + (size_t)blockIdx.z * 262144;
  u16t* C = Call + (size_t)blockIdx.z * 262144;
  const float scale = blockIdx.z == 0 ? LAM : 1.0f;
  __shared__ alignas(16) u16t As[64 * 32];
  __shared__ alignas(16) u16t Ws[64 * 32];
  const int tid = threadIdx.x;
  const int lane = tid & 63, wave = tid >> 6;
  const int r15 = lane & 15, rhi = lane >> 4;
  const int wr = wave >> 1, wc = wave & 1;
  const int m0 = blockIdx.x * 64, n0 = blockIdx.y * 64;
  const int arow = tid >> 2, acol = (tid & 3) * 8;
  const f32x4 fz = {0.f, 0.f, 0.f, 0.f};
  f32x4 acc[2][2] = {{fz, fz}, {fz, fz}};
  const u16t* Ap = A + (size_t)(m0 + arow) * 512 + acol;
  const u16t* Wp = W + (size_t)(n0 + arow) * 512 + acol;
  u16t* As0 = &As[tid * 8];
  u16t* Ws0 = &Ws[tid * 8];
  for (int kt = 0; kt < 512; kt += 32) {
    __syncthreads();
    GLDS16(Ap + kt, As0);
    GLDS16(Wp + kt, Ws0);
    asm volatile("s_waitcnt vmcnt(0)" ::: "memory");
    __syncthreads();
    bf16x8 af[2], bfv[2];
#pragma unroll
    for (int mi = 0; mi < 2; mi++)
      af[mi] = *(const bf16x8*)&As[(wr * 32 + mi * 16 + r15) * 32 + rhi * 8];
#pragma unroll
    for (int ni = 0; ni < 2; ni++)
      bfv[ni] = *(const bf16x8*)&Ws[(wc * 32 + ni * 16 + r15) * 32 + rhi * 8];
#pragma unroll
    for (int mi = 0; mi < 2; mi++)
#pragma unroll
      for (int ni = 0; ni < 2; ni++)
        acc[mi][ni] = mfma16(af[mi], bfv[ni], acc[mi][ni]);
  }
#pragma unroll
  for (int mi = 0; mi < 2; mi++)
#pragma unroll
    for (int ni = 0; ni < 2; ni++) {
      const int col = n0 + wc * 32 + ni * 16 + r15;
#pragma unroll
      for (int r = 0; r < 4; r++) {
        const int row = m0 + wr * 32 + mi * 16 + rhi * 4 + r;
        C[(size_t)row * 512 + col] = f2bf(acc[mi][ni][r] * scale);
      }
    }
}

// ---------------- composed bias (seg 0 scaled by LAM) ----------------
__global__ __launch_bounds__(256) void bias_mv(const float* __restrict__ in_w,
                                               const float* __restrict__ in_b,
                                               const float* __restrict__ b0,
                                               const float* __restrict__ b1,
                                               const float* __restrict__ b2v,
                                               float* __restrict__ out) {
  const int bi = blockIdx.x;                 // 24 blocks
  const int seg = bi >> 3, m0 = (bi & 7) * 64;
  const float* bvec = seg == 0 ? b0 : seg == 1 ? b1 : b2v;
  const int m = m0 + (threadIdx.x >> 2), q = threadIdx.x & 3;
  const float* row = in_w + (size_t)(seg * 512 + m) * 512 + q * 128;
  const float* bv = bvec + q * 128;
  float s = 0.f;
  for (int j = 0; j < 128; j++) s += row[j] * bv[j];
  s += __shfl_xor(s, 1); s += __shfl_xor(s, 2);
  if (q == 0) {
    float r2 = s + in_b[seg * 512 + m];
    out[seg * 512 + m] = seg == 0 ? r2 * LAM : r2;
  }
}

// ---------------- 128x128-tile GEMM, double-buffered LDS + counted vmcnt ----------------
template<int ACT, int OUTBF>
__global__ __launch_bounds__(256) void gemm_bt(
    const u16t* __restrict__ A, int lda,
    const u16t* __restrict__ W,
    const float* __restrict__ bias,
    void* __restrict__ Cp, int ldc, int K)
{
  __shared__ alignas(16) u16t As[2 * 128 * 32];
  __shared__ alignas(16) u16t Ws[2 * 128 * 32];
  const int tid  = threadIdx.x;
  const int lane = tid & 63, wave = tid >> 6;
  const int r15  = lane & 15, rhi = lane >> 4;
  const int wr   = wave >> 1, wc  = wave & 1;
  const int m0 = blockIdx.x * 128, n0 = blockIdx.y * 128;
  const int arow = tid >> 2, acol = (tid & 3) * 8;

  const f32x4 fz = {0.f, 0.f, 0.f, 0.f};
  f32x4 acc[4][4];
#pragma unroll
  for (int i = 0; i < 4; i++)
#pragma unroll
    for (int j = 0; j < 4; j++) acc[i][j] = fz;

  const u16t* Ap0 = A + (size_t)(m0 + arow) * lda + acol;
  const u16t* Ap1 = A + (size_t)(m0 + arow + 64) * lda + acol;
  const u16t* Wp0 = W + (size_t)(n0 + arow) * K + acol;
  const u16t* Wp1 = W + (size_t)(n0 + arow + 64) * K + acol;

  GLDS16(Ap0, &As[tid * 8]);
  GLDS16(Ap1, &As[(tid + 256) * 8]);
  GLDS16(Wp0, &Ws[tid * 8]);
  GLDS16(Wp1, &Ws[(tid + 256) * 8]);

  int cur = 0;
  for (int kt = 0; kt < K; kt += 32) {
    const int nxt = cur ^ 1;
    if (kt) __syncthreads();
    if (kt + 32 < K) {
      const int no = nxt * 4096;
      GLDS16(Ap0 + kt + 32, &As[no + tid * 8]);
      GLDS16(Ap1 + kt + 32, &As[no + (tid + 256) * 8]);
      GLDS16(Wp0 + kt + 32, &Ws[no + tid * 8]);
      GLDS16(Wp1 + kt + 32, &Ws[no + (tid + 256) * 8]);
      asm volatile("s_waitcnt vmcnt(4)" ::: "memory");
    } else {
      asm volatile("s_waitcnt vmcnt(0)" ::: "memory");
    }
    __syncthreads();
    const int cb = cur * 4096;
    bf16x8 af[4], bfv[4];
#pragma unroll
    for (int mi = 0; mi < 4; mi++)
      af[mi] = *(const bf16x8*)&As[cb + (wr * 64 + mi * 16 + r15) * 32 + rhi * 8];
#pragma unroll
    for (int ni = 0; ni < 4; ni++)
      bfv[ni] = *(const bf16x8*)&Ws[cb + (wc * 64 + ni * 16 + r15) * 32 + rhi * 8];
#pragma unroll
    for (int mi = 0; mi < 4; mi++)
#pragma unroll
      for (int ni = 0; ni < 4; ni++)
        acc[mi][ni] = mfma16(af[mi], bfv[ni], acc[mi][ni]);
    cur = nxt;
  }

#pragma unroll
  for (int mi = 0; mi < 4; mi++) {
#pragma unroll
    for (int ni = 0; ni < 4; ni++) {
      const int col = n0 + wc * 64 + ni * 16 + r15;
      const float bv = bias[col];
#pragma unroll
      for (int r = 0; r < 4; r++) {
        const int row = m0 + wr * 64 + mi * 16 + rhi * 4 + r;
        float v = acc[mi][ni][r] + bv;
        if (ACT == 1) v = v >= 0.f ? v : 0.01f * v;
        if (OUTBF) ((u16t*)Cp)[(size_t)row * ldc + col] = f2bf(v);
        else       ((float*)Cp)[(size_t)row * ldc + col] = v;
      }
    }
  }
}

// ---------------- 64x64-tile GEMM (out-proj), double-buffered ----------------
template<int ACT>
__global__ __launch_bounds__(256) void gemm64(
    const u16t* __restrict__ A, int lda,
    const u16t* __restrict__ W,
    const float* __restrict__ bias,
    u16t* __restrict__ Cp, int ldc, int K)
{
  __shared__ alignas(16) u16t As[2 * 64 * 32];
  __shared__ alignas(16) u16t Ws[2 * 64 * 32];
  const int tid  = threadIdx.x;
  const int lane = tid & 63, wave = tid >> 6;
  const int r15  = lane & 15, rhi = lane >> 4;
  const int wr   = wave >> 1, wc  = wave & 1;
  const int m0 = blockIdx.x * 64, n0 = blockIdx.y * 64;
  const int arow = tid >> 2, acol = (tid & 3) * 8;

  const f32x4 fz = {0.f, 0.f, 0.f, 0.f};
  f32x4 acc[2][2] = {{fz, fz}, {fz, fz}};

  const u16t* Ap = A + (size_t)(m0 + arow) * lda + acol;
  const u16t* Wp = W + (size_t)(n0 + arow) * K + acol;

  GLDS16(Ap, &As[tid * 8]);
  GLDS16(Wp, &Ws[tid * 8]);

  int cur = 0;
  for (int kt = 0; kt < K; kt += 32) {
    const int nxt = cur ^ 1;
    if (kt) __syncthreads();
    if (kt + 32 < K) {
      const int no = nxt * 2048;
      GLDS16(Ap + kt + 32, &As[no + tid * 8]);
      GLDS16(Wp + kt + 32, &Ws[no + tid * 8]);
      asm volatile("s_waitcnt vmcnt(2)" ::: "memory");
    } else {
      asm volatile("s_waitcnt vmcnt(0)" ::: "memory");
    }
    __syncthreads();
    const int cb = cur * 2048;
    bf16x8 af[2], bfv[2];
#pragma unroll
    for (int mi = 0; mi < 2; mi++)
      af[mi] = *(const bf16x8*)&As[cb + (wr * 32 + mi * 16 + r15) * 32 + rhi * 8];
#pragma unroll
    for (int ni = 0; ni < 2; ni++)
      bfv[ni] = *(const bf16x8*)&Ws[cb + (wc * 32 + ni * 16 + r15) * 32 + rhi * 8];
#pragma unroll
    for (int mi = 0; mi < 2; mi++)
#pragma unroll
      for (int ni = 0; ni < 2; ni++)
        acc[mi][ni] = mfma16(af[mi], bfv[ni], acc[mi][ni]);
    cur = nxt;
  }

#pragma unroll
  for (int mi = 0; mi < 2; mi++)
#pragma unroll
    for (int ni = 0; ni < 2; ni++) {
      const int col = n0 + wc * 32 + ni * 16 + r15;
      const float bv = bias[col];
#pragma unroll
      for (int r = 0; r < 4; r++) {
        const int row = m0 + wr * 32 + mi * 16 + rhi * 4 + r;
        float v = acc[mi][ni][r] + bv;
        if (ACT == 1) v = v >= 0.f ? v : 0.01f * v;
        Cp[(size_t)row * ldc + col] = f2bf(v);
      }
    }
}

// ---------------- sparse MoE + shared expert, 128x128 tiles, dbuf + dense indexing ----------------
#define MOE_MAX_TILES 200   // worst case: sum ceil(cnt_e/128) <= 136, + 64 shared
__global__ __launch_bounds__(256) void moe_shared(
    const u16t* __restrict__ x1b, const u16t* __restrict__ expwb,
    const float* __restrict__ expb,
    const u16t* __restrict__ shwb, const float* __restrict__ shb,
    const int* __restrict__ counts,
    const int* __restrict__ list, const float* __restrict__ wlist,
    u16t* __restrict__ out_slots, u16t* __restrict__ shrd)
{
  const int idx = blockIdx.x;
  int e = 0, base = 0, cnt = 0;
  for (; e < 8; e++) {
    cnt = counts[e];
    const int nt = (cnt + 127) >> 7;
    if (idx < base + nt) break;
    base += nt;
  }
  const bool sh = (e == 8);
  if (sh) {
    cnt = TT;
    if (idx - base >= 64) return;
  }
  const int m0 = (idx - base) * 128;
  if (m0 >= cnt) return;

  const int n0 = blockIdx.y * 128;
  __shared__ alignas(16) u16t As[2 * 128 * 32];
  __shared__ alignas(16) u16t Ws[2 * 128 * 32];
  __shared__ int tks[128];
  __shared__ float wws[128];
  const int tid  = threadIdx.x;
  const int lane = tid & 63, wave = tid >> 6;
  const int r15  = lane & 15, rhi = lane >> 4;
  const int wr   = wave >> 1, wc  = wave & 1;
  const int arow = tid >> 2, acol = (tid & 3) * 8;

  if (tid < 128) {
    if (sh) { tks[tid] = m0 + tid; wws[tid] = 1.f; }
    else {
      int i2 = m0 + tid; if (i2 >= cnt) i2 = cnt - 1;
      tks[tid] = list[e * 8192 + i2];
      wws[tid] = wlist[e * 8192 + i2];
    }
  }
  __syncthreads();
  const int tokA = sh ? tks[arow] : (tks[arow] >> 1);
  const int tokB = sh ? tks[arow + 64] : (tks[arow + 64] >> 1);

  const f32x4 fz = {0.f, 0.f, 0.f, 0.f};
  f32x4 acc[4][4];
#pragma unroll
  for (int i = 0; i < 4; i++)
#pragma unroll
    for (int j = 0; j < 4; j++) acc[i][j] = fz;

  const u16t* Ap0 = x1b + (size_t)tokA * 512 + acol;
  const u16t* Ap1 = x1b + (size_t)tokB * 512 + acol;
  const u16t* W  = (sh ? shwb : expwb + (size_t)e * 262144);
  const float* bias = sh ? shb : expb + e * 512;
  u16t* outp = sh ? shrd : out_slots;
  const u16t* Wp0 = W + (size_t)(n0 + arow) * 512 + acol;
  const u16t* Wp1 = Wp0 + (size_t)64 * 512;

  GLDS16(Ap0, &As[tid * 8]);
  GLDS16(Ap1, &As[(tid + 256) * 8]);
  GLDS16(Wp0, &Ws[tid * 8]);
  GLDS16(Wp1, &Ws[(tid + 256) * 8]);

  int cur = 0;
  for (int kt = 0; kt < 512; kt += 32) {
    const int nxt = cur ^ 1;
    if (kt) __syncthreads();
    if (kt + 32 < 512) {
      const int no = nxt * 4096;
      GLDS16(Ap0 + kt + 32, &As[no + tid * 8]);
      GLDS16(Ap1 + kt + 32, &As[no + (tid + 256) * 8]);
      GLDS16(Wp0 + kt + 32, &Ws[no + tid * 8]);
      GLDS16(Wp1 + kt + 32, &Ws[no + (tid + 256) * 8]);
      asm volatile("s_waitcnt vmcnt(4)" ::: "memory");
    } else {
      asm volatile("s_waitcnt vmcnt(0)" ::: "memory");
    }
    __syncthreads();
    const int cb = cur * 4096;
    bf16x8 af[4], bfv[4];
#pragma unroll
    for (int mi = 0; mi < 4; mi++)
      af[mi] = *(const bf16x8*)&As[cb + (wr * 64 + mi * 16 + r15) * 32 + rhi * 8];
#pragma unroll
    for (int ni = 0; ni < 4; ni++)
      bfv[ni] = *(const bf16x8*)&Ws[cb + (wc * 64 + ni * 16 + r15) * 32 + rhi * 8];
#pragma unroll
    for (int mi = 0; mi < 4; mi++)
#pragma unroll
      for (int ni = 0; ni < 4; ni++)
        acc[mi][ni] = mfma16(af[mi], bfv[ni], acc[mi][ni]);
    cur = nxt;
  }

#pragma unroll
  for (int mi = 0; mi < 4; mi++)
#pragma unroll
    for (int ni = 0; ni < 4; ni++) {
      const int col = n0 + wc * 64 + ni * 16 + r15;
      const float bv = bias[col];
#pragma unroll
      for (int r = 0; r < 4; r++) {
        const int rl = wr * 64 + mi * 16 + rhi * 4 + r;
        if (m0 + rl < cnt) {
          float z = acc[mi][ni][r] + bv;
          z = z >= 0.f ? z : 0.01f * z;
          outp[(size_t)tks[rl] * 512 + col] = f2bf(wws[rl] * z);
        }
      }
    }
}

// ---------------- flash attention v3: 8 waves / 128 q-rows per block ----------------
__global__ __launch_bounds__(512) void attn_kernel(
    const u16t* __restrict__ qkv, u16t* __restrict__ ao)
{
  const int bh = blockIdx.x;
  const int b = bh >> 3, h = bh & 7;
  const int qg = blockIdx.y;
  const int tid  = threadIdx.x;
  const int lane = tid & 63, wave = tid >> 6;
  const int r15  = lane & 15, rhi = lane >> 4;

  __shared__ alignas(16) u16t Ks[128 * 72];
  __shared__ alignas(16) u16t Vt[64 * 136];

  const int qrow = qg * 128 + (wave >> 2) * 64 + (wave & 3) * 16 + r15;
  const size_t qoff = ((size_t)qrow * BB + b) * 1536 + h * HDD;
  const bf16x8 qf0 = *(const bf16x8*)&qkv[qoff + rhi * 8];
  const bf16x8 qf1 = *(const bf16x8*)&qkv[qoff + 32 + rhi * 8];

  const f32x4 fz = {0.f, 0.f, 0.f, 0.f};
  f32x4 oa[4] = {fz, fz, fz, fz};
  float psum = 0.f;

  const int krow = tid >> 2, kchunk = (tid & 3) * 16;
  const int vd0 = (wave & 3) * 16 + (lane >> 5) * 8;
  const int vkv = (wave >> 2) * 64 + (lane & 31) * 2;

  u16x8 kA0, kA1, vA0, vA1;
  {
    const size_t kb = ((size_t)krow * BB + b) * 1536 + h * HDD + 512 + kchunk;
    kA0 = *(const u16x8*)&qkv[kb];
    kA1 = *(const u16x8*)&qkv[kb + 8];
    const size_t v0 = ((size_t)vkv * BB + b) * 1536 + h * HDD + 1024 + vd0;
    vA0 = *(const u16x8*)&qkv[v0];
    vA1 = *(const u16x8*)&qkv[v0 + (size_t)BB * 1536];
  }

  for (int t = 0; t < 8; t++) {
    __syncthreads();
    {
      u16t* kd = &Ks[krow * 72 + kchunk];
      *(u16x8*)&kd[0] = kA0;
      *(u16x8*)&kd[8] = kA1;
    }
#pragma unroll
    for (int j = 0; j < 8; j++) {
      unsigned int w = (unsigned int)vA0[j] | ((unsigned int)vA1[j] << 16);
      *(unsigned int*)&Vt[(vd0 + j) * 136 + vkv] = w;
    }
    if (t < 7) {
      const int kv0n = (t + 1) * 128;
      const size_t kb = ((size_t)(kv0n + krow) * BB + b) * 1536 + h * HDD + 512 + kchunk;
      kA0 = *(const u16x8*)&qkv[kb];
      kA1 = *(const u16x8*)&qkv[kb + 8];
      const size_t v0 = ((size_t)(kv0n + vkv) * BB + b) * 1536 + h * HDD + 1024 + vd0;
      vA0 = *(const u16x8*)&qkv[v0];
      vA1 = *(const u16x8*)&qkv[v0 + (size_t)BB * 1536];
    }
    __syncthreads();

    f32x4 s[8];
    __builtin_amdgcn_s_setprio(1);
#pragma unroll
    for (int nt = 0; nt < 8; nt++) {
      const u16t* kr = &Ks[(nt * 16 + r15) * 72];
      bf16x8 k0 = *(const bf16x8*)&kr[rhi * 8];
      bf16x8 k1 = *(const bf16x8*)&kr[32 + rhi * 8];
      f32x4 acc = fz;
      acc = mfma16(k0, qf0, acc);
      acc = mfma16(k1, qf1, acc);
      s[nt] = acc;
    }
    __builtin_amdgcn_s_setprio(0);

    unsigned int P2[8][2];
#pragma unroll
    for (int nt = 0; nt < 8; nt++) {
#pragma unroll
      for (int r = 0; r < 4; r++) {
        s[nt][r] = exp2f(s[nt][r]);
        psum += s[nt][r];
      }
      asm("v_cvt_pk_bf16_f32 %0, %1, %2" : "=v"(P2[nt][0]) : "v"(s[nt][0]), "v"(s[nt][1]));
      asm("v_cvt_pk_bf16_f32 %0, %1, %2" : "=v"(P2[nt][1]) : "v"(s[nt][2]), "v"(s[nt][3]));
    }

    __builtin_amdgcn_s_setprio(1);
#pragma unroll
    for (int c = 0; c < 4; c++) {
      union { unsigned int w[4]; bf16x8 v; } pf;
      pf.w[0] = P2[2 * c][0];     pf.w[1] = P2[2 * c][1];
      pf.w[2] = P2[2 * c + 1][0]; pf.w[3] = P2[2 * c + 1][1];
#pragma unroll
      for (int dd = 0; dd < 4; dd++) {
        const u16t* vr = &Vt[(dd * 16 + r15) * 136 + c * 32 + rhi * 4];
        union { u16x4 h[2]; bf16x8 v; } vb;
        vb.h[0] = *(const u16x4*)&vr[0];
        vb.h[1] = *(const u16x4*)&vr[16];
        oa[dd] = mfma16(vb.v, pf.v, oa[dd]);
      }
    }
    __builtin_amdgcn_s_setprio(0);
  }

  float ls = psum;
  ls += __shfl_xor(ls, 16);
  ls += __shfl_xor(ls, 32);
  const float inv = 1.f / ls;
  const size_t obase = ((size_t)qrow * BB + b) * EE + h * HDD;
#pragma unroll
  for (int dd = 0; dd < 4; dd++) {
    u16x4 o = { f2bf(oa[dd][0] * inv), f2bf(oa[dd][1] * inv),
                f2bf(oa[dd][2] * inv), f2bf(oa[dd][3] * inv) };
    *(u16x4*)&ao[obase + dd * 16 + rhi * 4] = o;
  }
}

// ---------------- fused LN1 + gate (wave per token) ----------------
__device__ __forceinline__ float wave_sum(float v) {
#pragma unroll
  for (int off = 1; off < 64; off <<= 1) v += __shfl_xor(v, off);
  return v;
}

__global__ __launch_bounds__(256) void ln1_gate(
    const float* __restrict__ x, const u16t* __restrict__ aopb,
    const float* __restrict__ g, const float* __restrict__ be,
    const float* __restrict__ gw, const float* __restrict__ gb,
    u16t* __restrict__ x1b,
    int* __restrict__ tok_pack, float2* __restrict__ tok_w,
    float* __restrict__ partials)
{
  const int wave = threadIdx.x >> 6, lane = threadIdx.x & 63;
  const int t = blockIdx.x * 4 + wave;
  const size_t base = (size_t)t * EE + lane * 8;
  float4 a0 = *(const float4*)&x[base], a1 = *(const float4*)&x[base + 4];
  u16x8 ap = *(const u16x8*)&aopb[base];
  float v[8] = { a0.x + bf2f(ap[0]), a0.y + bf2f(ap[1]), a0.z + bf2f(ap[2]), a0.w + bf2f(ap[3]),
                 a1.x + bf2f(ap[4]), a1.y + bf2f(ap[5]), a1.z + bf2f(ap[6]), a1.w + bf2f(ap[7]) };
  float s = 0.f;
#pragma unroll
  for (int i = 0; i < 8; i++) s += v[i];
  const float mean = wave_sum(s) * (1.f / EE);
  float vs = 0.f;
#pragma unroll
  for (int i = 0; i < 8; i++) { v[i] -= mean; vs += v[i] * v[i]; }
  const float inv = rsqrtf(wave_sum(vs) * (1.f / EE) + 1e-5f);
  float4 g0 = *(const float4*)&g[lane * 8],  g1 = *(const float4*)&g[lane * 8 + 4];
  float4 b0 = *(const float4*)&be[lane * 8], b1 = *(const float4*)&be[lane * 8 + 4];
  float o[8] = { v[0]*inv*g0.x + b0.x, v[1]*inv*g0.y + b0.y, v[2]*inv*g0.z + b0.z, v[3]*inv*g0.w + b0.w,
                 v[4]*inv*g1.x + b1.x, v[5]*inv*g1.y + b1.y, v[6]*inv*g1.z + b1.z, v[7]*inv*g1.w + b1.w };
  u16x8 ob = { f2bf(o[0]), f2bf(o[1]), f2bf(o[2]), f2bf(o[3]),
               f2bf(o[4]), f2bf(o[5]), f2bf(o[6]), f2bf(o[7]) };
  *(u16x8*)&x1b[base] = ob;

  float pe[8];
  float mx = -1e30f;
#pragma unroll
  for (int e = 0; e < 8; e++) {
    float4 ga = *(const float4*)&gw[e * EE + lane * 8];
    float4 gB = *(const float4*)&gw[e * EE + lane * 8 + 4];
    float d = o[0]*ga.x + o[1]*ga.y + o[2]*ga.z + o[3]*ga.w
            + o[4]*gB.x + o[5]*gB.y + o[6]*gB.z + o[7]*gB.w;
#pragma unroll
    for (int off = 1; off < 64; off <<= 1) d += __shfl_xor(d, off);
    pe[e] = d + gb[e];
    mx = fmaxf(mx, pe[e]);
  }
  float se = 0.f;
#pragma unroll
  for (int e = 0; e < 8; e++) { pe[e] = __expf(pe[e] - mx); se += pe[e]; }
  const float invs = 1.f / se;
#pragma unroll
  for (int e = 0; e < 8; e++) pe[e] *= invs;
  float v1 = -1.f; int i1 = 0;
#pragma unroll
  for (int e = 0; e < 8; e++) if (pe[e] > v1) { v1 = pe[e]; i1 = e; }
  float v2 = -1.f; int i2 = -1;
#pragma unroll
  for (int e = 0; e < 8; e++) if (e != i1 && pe[e] > v2) { v2 = pe[e]; i2 = e; }
  const float denom = 1.f / (v1 + v2);
  if (lane == 0) {
    tok_pack[t] = i1 | (i2 << 8);
    float2 w; w.x = v1 * denom; w.y = v2 * denom;
    tok_w[t] = w;
  }
  __shared__ float fb[4][8], pb[4][8];
  if (lane < 8) {
    fb[wave][lane] = (lane == i1 || lane == i2) ? 1.f : 0.f;
    pb[wave][lane] = pe[lane];
  }
  __syncthreads();
  if (threadIdx.x < 8) {
    const int e = threadIdx.x;
    partials[(size_t)blockIdx.x * 16 + e]     = fb[0][e] + fb[1][e] + fb[2][e] + fb[3][e];
    partials[(size_t)blockIdx.x * 16 + 8 + e] = pb[0][e] + pb[1][e] + pb[2][e] + pb[3][e];
  }
}

// ---------------- LN2 (bf16 inputs) ----------------
__global__ __launch_bounds__(256) void ln2_kernel(
    const u16t* __restrict__ x1b, const u16t* __restrict__ slots,
    const u16t* __restrict__ sh,
    const float* __restrict__ g, const float* __restrict__ be,
    float* __restrict__ out)
{
  const int wave = threadIdx.x >> 6, lane = threadIdx.x & 63;
  const int t = blockIdx.x * 4 + wave;
  const size_t base = (size_t)t * EE + lane * 8;
  u16x8 xv = *(const u16x8*)&x1b[base];
  u16x8 m0 = *(const u16x8*)&slots[(size_t)(2 * t) * EE + lane * 8];
  u16x8 m1 = *(const u16x8*)&slots[(size_t)(2 * t + 1) * EE + lane * 8];
  u16x8 sv = *(const u16x8*)&sh[base];
  float v[8];
#pragma unroll
  for (int i = 0; i < 8; i++)
    v[i] = bf2f(xv[i]) + bf2f(m0[i]) + bf2f(m1[i]) + bf2f(sv[i]);
  float s = 0.f;
#pragma unroll
  for (int i = 0; i < 8; i++) s += v[i];
  const float mean = wave_sum(s) * (1.f / EE);
  float vs = 0.f;
#pragma unroll
  for (int i = 0; i < 8; i++) { v[i] -= mean; vs += v[i] * v[i]; }
  const float inv = rsqrtf(wave_sum(vs) * (1.f / EE) + 1e-5f);
  float4 g0 = *(const float4*)&g[lane * 8],  g1 = *(const float4*)&g[lane * 8 + 4];
  float4 b0 = *(const float4*)&be[lane * 8], b1 = *(const float4*)&be[lane * 8 + 4];
  *(float4*)&out[base] = make_float4(v[0]*inv*g0.x + b0.x, v[1]*inv*g0.y + b0.y,
                                     v[2]*inv*g0.z + b0.z, v[3]*inv*g0.w + b0.w);
  *(float4*)&out[base + 4] = make_float4(v[4]*inv*g1.x + b1.x, v[5]*inv*g1.y + b1.y,
                                         v[6]*inv*g1.z + b1.z, v[7]*inv*g1.w + b1.w);
}

// ---------------- deterministic list build + loss reduce (grid 9, block 512) ----------------
__global__ __launch_bounds__(512) void build_lists(
    const int* __restrict__ tok_pack, const float2* __restrict__ tok_w,
    int* __restrict__ counts, int* __restrict__ list, float* __restrict__ wlist,
    const float* __restrict__ partials, float* __restrict__ loss_out)
{
  if (blockIdx.x == 8) {
    __shared__ float acc2[32][16];
    __shared__ float fin[16];
    const int c = threadIdx.x & 15, grp = threadIdx.x >> 4;   // 0..31
    float s = 0.f;
    for (int i = grp; i < 2048; i += 32) s += partials[(size_t)i * 16 + c];
    acc2[grp][c] = s;
    __syncthreads();
    if (threadIdx.x < 16) {
      float t2 = 0.f;
      for (int g2 = 0; g2 < 32; g2++) t2 += acc2[g2][threadIdx.x];
      fin[threadIdx.x] = t2;
    }
    __syncthreads();
    if (threadIdx.x == 0) {
      float loss = 0.f;
      for (int e = 0; e < 8; e++)
        loss += (fin[e] * (1.f / TT)) * (fin[8 + e] * (1.f / TT));
      loss_out[0] = loss * 8.f;
    }
    return;
  }
  const int e = blockIdx.x;
  const int tid = threadIdx.x;
  const int lane = tid & 63, wave = tid >> 6;   // 8 waves
  __shared__ int wtot[8];
  __shared__ int runb;
  if (tid == 0) runb = 0;
  __syncthreads();
  for (int c = 0; c < 16; c++) {
    const int t = c * 512 + tid;
    const int pk = tok_pack[t];
    const int i1 = pk & 255, i2 = (pk >> 8) & 255;
    const bool s1 = (i1 == e);
    const bool flag = s1 || (i2 == e);
    const unsigned long long mask = __ballot(flag);
    if (lane == 63) wtot[wave] = __popcll(mask);
    __syncthreads();
    int wbase = 0;
#pragma unroll
    for (int w2 = 0; w2 < 8; w2++) if (w2 < wave) wbase += wtot[w2];
    int btot = 0;
#pragma unroll
    for (int w2 = 0; w2 < 8; w2++) btot += wtot[w2];
    if (flag) {
      const int pre = __popcll(mask & ((1ull << lane) - 1ull));
      const int pos = runb + wbase + pre;
      list[e * 8192 + pos] = 2 * t + (s1 ? 0 : 1);
      float2 w = tok_w[t];
      wlist[e * 8192 + pos] = s1 ? w.x : w.y;
    }
    __syncthreads();
    if (tid == 0) runb += btot;
    __syncthreads();
  }
  if (tid == 0) counts[e] = runb;
}

// ---------------- host-side launcher ----------------
extern "C" void kernel_launch(void* const* d_in, const int* in_sizes, int n_in,
                              void* d_out, int out_size, void* d_ws, size_t ws_size,
                              hipStream_t stream) {
  const float* x    = (const float*)d_in[0];
  const float* wq   = (const float*)d_in[1];
  const float* bq   = (const float*)d_in[2];
  const float* wk   = (const float*)d_in[3];
  const float* bk   = (const float*)d_in[4];
  const float* wv   = (const float*)d_in[5];
  const float* bv   = (const float*)d_in[6];
  const float* in_w = (const float*)d_in[7];
  const float* in_b = (const float*)d_in[8];
  const float* out_w= (const float*)d_in[9];
  const float* out_b= (const float*)d_in[10];
  const float* ln1g = (const float*)d_in[11];
  const float* ln1b = (const float*)d_in[12];
  const float* ln2g = (const float*)d_in[13];
  const float* ln2b = (const float*)d_in[14];
  const float* shw  = (const float*)d_in[15];
  const float* shb  = (const float*)d_in[16];
  const float* gw   = (const float*)d_in[17];
  const float* gb   = (const float*)d_in[18];
  const float* expw = (const float*)d_in[19];
  const float* expb = (const float*)d_in[20];

  char* ws = (char*)d_ws;
  // --- static region ---
  u16t* xb     = (u16t*)(ws + 0);          // 8 MB
  u16t* inwb   = (u16t*)(ws + 8388608);    // 1.5 MB
  u16t* w3t    = (u16t*)(ws + 9961472);    // 1.5 MB
  u16t* w2big  = (u16t*)(ws + 11534336);   // 1.5 MB
  u16t* outwb  = (u16t*)(ws + 13107200);   // 0.5 MB
  u16t* shwb   = (u16t*)(ws + 13631488);   // 0.5 MB
  u16t* expwb  = (u16t*)(ws + 14155776);   // 4 MB
  float* b2    = (float*)(ws + 18350080);  // 6 KB
  int*  tok_pack = (int*)(ws + 18356224);  // 32 KB
  float2* tok_w  = (float2*)(ws + 18388992); // 64 KB
  int*  counts = (int*)(ws + 18454528);
  int*  list   = (int*)(ws + 18454656);    // 256 KB
  float* wlist = (float*)(ws + 18716800);  // 256 KB
  float* parts = (float*)(ws + 18978944);  // 128 KB
  // --- overlay pool ---
  const size_t S = 19110016;
  u16t* qkvb   = (u16t*)(ws + S);                 // 24 MB: stage1 -> attn
  u16t* aopb   = (u16t*)(ws + S);                 // 8 MB: outproj -> ln1 (qkvb dead)
  u16t* x1b    = (u16t*)(ws + S + 16777216);      // 8 MB: ln1 -> moe/shared/ln2
  u16t* oslots = (u16t*)(ws + S);                 // 16 MB: moe -> ln2 (aopb dead)
  u16t* aob    = (u16t*)(ws + 0);                 // 8 MB: attn -> outproj (xb dead)
  u16t* shrd   = (u16t*)(ws + 0);                 // 8 MB: moe_shared -> ln2 (aob dead)
  float* outp  = (float*)d_out;

  dim3 blk(256);
  // all converts + QKV-weight transpose in one dispatch (7424 + 192 blocks)
  cvt_all<<<7616, blk, 0, stream>>>(x, in_w, out_w, shw, expw, wq, wk, wv,
                                    xb, inwb, outwb, shwb, expwb, w3t);
  // weight/bias composition (Q segment pre-scaled by log2e/8)
  compose_k<<<dim3(8, 8, 3), blk, 0, stream>>>(inwb, w3t, w2big);
  bias_mv<<<24, blk, 0, stream>>>(in_w, in_b, bq, bk, bv, b2);
  // fused QKV projection -> q|k|v packed (ldc 1536)
  gemm_bt<0,1><<<dim3(64, 12), blk, 0, stream>>>(xb, EE, w2big, b2, qkvb, 1536, EE);
  // attention (512-thread blocks, 128 q-rows each)
  attn_kernel<<<dim3(64, 8), dim3(512), 0, stream>>>(qkvb, aob);
  // out projection (bf16 out, 64x64 tiles)
  gemm64<0><<<dim3(128, 8), blk, 0, stream>>>(aob, EE, outwb, out_b, aopb, EE, EE);
  // fused LN1 + gate
  ln1_gate<<<2048, blk, 0, stream>>>(x, aopb, ln1g, ln1b, gw, gb, x1b, tok_pack, tok_w, parts);
  // list build + loss reduce (grid 9, block 512)
  build_lists<<<9, dim3(512), 0, stream>>>(tok_pack, tok_w, counts, list, wlist,
                                           parts, outp + (size_t)TT * EE);
  // sparse MoE + shared expert (128x128 tiles, dbuf, dense tile indexing)
  moe_shared<<<dim3(MOE_MAX_TILES, 4), blk, 0, stream>>>(x1b, expwb, expb, shwb, shb,
                                                         counts, list, wlist, oslots, shrd);
  // LN2 -> output (f32)
  ln2_kernel<<<2048, blk, 0, stream>>>(x1b, oslots, shrd, ln2g, ln2b, outp);
}